// Round 7
// baseline (792.181 us; speedup 1.0000x reference)
//
#include <hip/hip_runtime.h>
#include <hip/hip_bf16.h>
#include <math.h>

#define B_  4
#define S_  2048
#define D_  1024
#define H_  16
#define HD_ 64
#define SD_  (S_*D_)        // 2097152
#define SHD_ (S_*HD_)       // 131072

typedef __attribute__((ext_vector_type(8))) short          bf16x8;   // MFMA A/B frag (4 VGPRs)
typedef __attribute__((ext_vector_type(4))) float          f32x4;    // MFMA C/D frag
typedef __attribute__((ext_vector_type(8))) unsigned short us8;
typedef __attribute__((ext_vector_type(4))) unsigned short us4;

__device__ __forceinline__ unsigned short f2bf(float x) {  // RNE float->bf16
  unsigned int u = __float_as_uint(x);
  u += 0x7fffu + ((u >> 16) & 1u);
  return (unsigned short)(u >> 16);
}
__device__ __forceinline__ float bf2f(unsigned short u) {
  return __uint_as_float(((unsigned int)u) << 16);
}
// base-2 exp via v_exp_f32 directly (NOT __exp2f: glibc macro collision)
__device__ __forceinline__ float exp2f_fast(float x) {
  return __builtin_amdgcn_exp2f(x);
}

// async global->LDS, 16B per lane: wave-uniform LDS base + lane*16 (m104).
__device__ __forceinline__ void gload16(const unsigned short* g, unsigned short* l) {
  __builtin_amdgcn_global_load_lds(
      (const __attribute__((address_space(1))) unsigned int*)g,
      (__attribute__((address_space(3))) unsigned int*)l,
      16, 0, 0);
}

// ---------------------------------------------------------------------------
// fp32 -> bf16 converts
// ---------------------------------------------------------------------------
__global__ __launch_bounds__(256) void cvt_a(const float* __restrict__ s,
                                             unsigned short* __restrict__ d)
{
  int i = blockIdx.x * 256 + threadIdx.x;          // float4 index
  float4 v = ((const float4*)s)[i];
  us4 o = { f2bf(v.x), f2bf(v.y), f2bf(v.z), f2bf(v.w) };
  *(us4*)(d + (size_t)i * 4) = o;
}

__global__ __launch_bounds__(256) void cvt_w(const float* __restrict__ w0,
                                             const float* __restrict__ w1,
                                             const float* __restrict__ w2,
                                             const float* __restrict__ w3,
                                             unsigned short* __restrict__ dst)
{
  const float* s = (blockIdx.y == 0) ? w0 : (blockIdx.y == 1) ? w1
                 : (blockIdx.y == 2) ? w2 : w3;
  unsigned short* d = dst + (size_t)blockIdx.y * 1024 * 1024;
  int i = blockIdx.x * 256 + threadIdx.x;
  float4 v = ((const float4*)s)[i];
  us4 o = { f2bf(v.x), f2bf(v.y), f2bf(v.z), f2bf(v.w) };
  *(us4*)(d + (size_t)i * 4) = o;
}

// ---------------------------------------------------------------------------
// bf16 MFMA GEMM (m97 structure): C[8192,1024] = A @ W^T + bias, bf16 out
// (flat row-major — correct for the reference's flat head-view by construction).
// 128x128 tile, BK=32, 256 thr = 4 waves (2x2), 4x4 16x16 tiles per wave.
// ---------------------------------------------------------------------------
__global__ __launch_bounds__(256) void gemm_mfma(
    const unsigned short* __restrict__ A,    // [8192,1024] bf16
    const unsigned short* __restrict__ Wb,   // [1024,1024] bf16, row n = out col
    const float* __restrict__ bias,
    unsigned short* __restrict__ Cb)
{
  __shared__ unsigned short As[128 * 32];   // [row][k] 8 KB
  __shared__ unsigned short Bs[128 * 32];   // [ncol][k] 8 KB

  const int tid  = threadIdx.x;
  const int lane = tid & 63;
  const int w    = tid >> 6;
  const int wm   = w >> 1, wn = w & 1;
  const int l16  = lane & 15, quad = lane >> 4;
  const int n0 = blockIdx.x * 128;
  const int m0 = blockIdx.y * 128;

  f32x4 acc[4][4];
#pragma unroll
  for (int mt = 0; mt < 4; ++mt)
#pragma unroll
    for (int nt = 0; nt < 4; ++nt) acc[mt][nt] = (f32x4){0.f, 0.f, 0.f, 0.f};

  const int srow = lane >> 2;          // 0..15 row within 16-row slab
  const int sseg = (lane & 3) * 8;     // ushort offset within 32-elem row

  for (int kt = 0; kt < 32; ++kt) {
    const int kofs = kt * 32;
#pragma unroll
    for (int t = 0; t < 2; ++t) {
      const int r = w * 32 + t * 16 + srow;          // 0..127
      gload16(A  + (size_t)(m0 + r) * 1024 + kofs + sseg, &As[r * 32 + sseg]);
      gload16(Wb + (size_t)(n0 + r) * 1024 + kofs + sseg, &Bs[r * 32 + sseg]);
    }
    __syncthreads();   // drains vmcnt (global_load_lds) + barrier

    bf16x8 af[4], bfr[4];
#pragma unroll
    for (int mt = 0; mt < 4; ++mt)
      af[mt] = *(const bf16x8*)&As[(wm * 64 + mt * 16 + l16) * 32 + quad * 8];
#pragma unroll
    for (int nt = 0; nt < 4; ++nt)
      bfr[nt] = *(const bf16x8*)&Bs[(wn * 64 + nt * 16 + l16) * 32 + quad * 8];
#pragma unroll
    for (int mt = 0; mt < 4; ++mt)
#pragma unroll
      for (int nt = 0; nt < 4; ++nt)
        acc[mt][nt] = __builtin_amdgcn_mfma_f32_16x16x32_bf16(
            af[mt], bfr[nt], acc[mt][nt], 0, 0, 0);
    __syncthreads();   // frag reads done before next stage overwrites
  }

  // C-layout: col=l16, row=quad*4+reg  (m89-verified)
#pragma unroll
  for (int nt = 0; nt < 4; ++nt) {
    const int ncol = n0 + wn * 64 + nt * 16 + l16;
    const float bv = bias[ncol];
#pragma unroll
    for (int mt = 0; mt < 4; ++mt) {
      const int row = m0 + wm * 64 + mt * 16 + quad * 4;
#pragma unroll
      for (int reg = 0; reg < 4; ++reg)
        Cb[(size_t)(row + reg) * 1024 + ncol] = f2bf(acc[mt][nt][reg] + bv);
    }
  }
}

// ---------------------------------------------------------------------------
// V transpose: Vt[bh][d][s] = Vflat[bh*131072 + s*64 + d]  (flat indices,
// so the reference's scrambled head-view is handled automatically).
// ---------------------------------------------------------------------------
__global__ __launch_bounds__(256) void vtrans(
    const unsigned short* __restrict__ V, unsigned short* __restrict__ Vt)
{
  __shared__ unsigned short t[64][72];   // t[s][d], padded rows
  const int tid = threadIdx.x;
  const int st  = blockIdx.x;            // s-tile 0..31
  const int bh  = blockIdx.y;            // 0..63
  const unsigned short* src = V + (size_t)bh * SHD_ + (size_t)st * 4096;

#pragma unroll
  for (int u = tid; u < 512; u += 256) {           // 512 us8 chunks = 8 KB
    us8 vv = ((const us8*)src)[u];
    int s  = u >> 3;
    int dg = (u & 7) * 8;
    *(us8*)&t[s][dg] = vv;
  }
  __syncthreads();

  unsigned short* dst = Vt + (size_t)bh * SHD_ + st * 64;
#pragma unroll
  for (int u = tid; u < 1024; u += 256) {          // 64 d-rows x 16 us4 chunks
    int d  = u >> 4;
    int s4 = (u & 15) * 4;
    us4 o = { t[s4][d], t[s4 + 1][d], t[s4 + 2][d], t[s4 + 3][d] };
    *(us4*)(dst + (size_t)d * 2048 + s4) = o;
  }
}

// ---------------------------------------------------------------------------
// Barrier-free MFMA flash attention, diagonal-paired, K-prefetch double-buffer.
// WG p (0..15) processes Q-tiles {p, 31-p} -> uniform 33 j-iters per WG.
// K frags for jt+1 issued BEFORE body(jt) and consumed next trip (cross-BB
// liveness: compiler cannot sink them). Pad mask staged in LDS once.
// Base-2 online softmax; causal compare only on the diagonal tile.
// ---------------------------------------------------------------------------
__global__ __launch_bounds__(256, 4) void attn_mfma(
    unsigned short* __restrict__ Qb, const unsigned short* __restrict__ Kb,
    const unsigned short* __restrict__ Vt, const int* __restrict__ pad)
{
  __shared__ unsigned short Ps[4][16][72];  // per-wave P strip, 9216 B
  __shared__ int padS[2048];                // this batch's pad mask, 8 KB

  const int tid  = threadIdx.x;
  const int lane = tid & 63;
  const int w    = tid >> 6;
  const int p    = blockIdx.x;     // pair index 0..15
  const int bh   = blockIdx.y;     // 0..63
  const int b    = bh >> 4;
  const size_t base = (size_t)bh * SHD_;
  const int l16  = lane & 15;
  const int quad = lane >> 4;
  const float SC = 0.18033688011112042f;   // 0.125 * log2(e)  [base-2 softmax]

  for (int u = tid; u < 2048; u += 256) padS[u] = pad[b * S_ + u];
  __syncthreads();   // once per kernel; padS read-only afterwards

  const unsigned short* Kbb = Kb + base;
  const unsigned short* Vtb = Vt + base;

  for (int half = 0; half < 2; ++half) {
    const int it = half ? (31 - p) : p;

    bf16x8 qfrag[2];
    {
      const unsigned short* qrow = Qb + base + (size_t)(it * 64 + w * 16 + l16) * 64;
      qfrag[0] = *(const bf16x8*)(qrow + quad * 8);
      qfrag[1] = *(const bf16x8*)(qrow + 32 + quad * 8);
    }

    f32x4 oacc[4];
#pragma unroll
    for (int dt = 0; dt < 4; ++dt) oacc[dt] = (f32x4){0.f, 0.f, 0.f, 0.f};
    float mrow[4], lrow[4];
#pragma unroll
    for (int r = 0; r < 4; ++r) { mrow[r] = -INFINITY; lrow[r] = 0.f; }

    auto loadK = [&](int j, bf16x8* kf) {
#pragma unroll
      for (int ct = 0; ct < 4; ++ct) {
        const unsigned short* kr = Kbb + (size_t)(j * 64 + ct * 16 + l16) * 64;
        kf[2 * ct]     = *(const bf16x8*)(kr + quad * 8);
        kf[2 * ct + 1] = *(const bf16x8*)(kr + 32 + quad * 8);
      }
    };

    auto body = [&](int jt, const bf16x8* kf) {
      // ---- QK^T from prefetched K frags ----
      f32x4 sacc[4];
#pragma unroll
      for (int ct = 0; ct < 4; ++ct) {
        f32x4 c = (f32x4){0.f, 0.f, 0.f, 0.f};
        c = __builtin_amdgcn_mfma_f32_16x16x32_bf16(qfrag[0], kf[2 * ct],     c, 0, 0, 0);
        c = __builtin_amdgcn_mfma_f32_16x16x32_bf16(qfrag[1], kf[2 * ct + 1], c, 0, 0, 0);
        sacc[ct] = c;
      }

      // ---- V^T frag loads: in flight during softmax ----
      bf16x8 vf[8];
#pragma unroll
      for (int dt = 0; dt < 4; ++dt) {
        const unsigned short* vr = Vtb + (size_t)(dt * 16 + l16) * 2048 + jt * 64;
        vf[2 * dt]     = *(const bf16x8*)(vr + quad * 8);
        vf[2 * dt + 1] = *(const bf16x8*)(vr + 32 + quad * 8);
      }

      int padv[4];
#pragma unroll
      for (int ct = 0; ct < 4; ++ct) padv[ct] = padS[jt * 64 + ct * 16 + l16];

      const bool diag = (jt == it);           // wave-uniform
      const int grow0 = it * 64 + w * 16 + quad * 4;
      float alpha[4], pm[4][4];
#pragma unroll
      for (int reg = 0; reg < 4; ++reg) {
        float lg[4];
        float mx = -INFINITY;
#pragma unroll
        for (int ct = 0; ct < 4; ++ct) {
          bool ok = (padv[ct] != 0);
          if (diag) ok = ok && (jt * 64 + ct * 16 + l16 <= grow0 + reg);
          lg[ct] = ok ? sacc[ct][reg] * SC : -INFINITY;
          mx = fmaxf(mx, lg[ct]);
        }
#pragma unroll
        for (int off = 1; off < 16; off <<= 1) mx = fmaxf(mx, __shfl_xor(mx, off, 64));
        float mnew = fmaxf(mrow[reg], mx);
        float a    = exp2f_fast(mrow[reg] - mnew);   // base-2 domain throughout
        float sm   = 0.f;
#pragma unroll
        for (int ct = 0; ct < 4; ++ct) {
          float pe = exp2f_fast(lg[ct] - mnew);      // masked -> 2^(-inf)=0
          pm[reg][ct] = pe;
          sm += pe;
        }
#pragma unroll
        for (int off = 1; off < 16; off <<= 1) sm += __shfl_xor(sm, off, 64);
        lrow[reg]  = lrow[reg] * a + sm;
        mrow[reg]  = mnew;
        alpha[reg] = a;
      }
#pragma unroll
      for (int dt = 0; dt < 4; ++dt)
#pragma unroll
        for (int reg = 0; reg < 4; ++reg) oacc[dt][reg] *= alpha[reg];

      // ---- P: C-layout -> A-layout via per-wave LDS strip (no barrier) ----
#pragma unroll
      for (int reg = 0; reg < 4; ++reg)
#pragma unroll
        for (int ct = 0; ct < 4; ++ct)
          Ps[w][quad * 4 + reg][ct * 16 + l16] = f2bf(pm[reg][ct]);

      bf16x8 pfrag0 = *(const bf16x8*)&Ps[w][l16][quad * 8];
      bf16x8 pfrag1 = *(const bf16x8*)&Ps[w][l16][32 + quad * 8];

      // ---- PV ----
#pragma unroll
      for (int dt = 0; dt < 4; ++dt) {
        oacc[dt] = __builtin_amdgcn_mfma_f32_16x16x32_bf16(pfrag0, vf[2 * dt],     oacc[dt], 0, 0, 0);
        oacc[dt] = __builtin_amdgcn_mfma_f32_16x16x32_bf16(pfrag1, vf[2 * dt + 1], oacc[dt], 0, 0, 0);
      }
    };

    // software-pipelined loop: prefetch K(jt+1) before body(jt)
    bf16x8 kfa[8], kfb[8];
    loadK(0, kfa);
    int jt = 0;
    while (true) {
      if (jt < it) loadK(jt + 1, kfb);
      body(jt, kfa);
      if (++jt > it) break;
      if (jt < it) loadK(jt + 1, kfa);
      body(jt, kfb);
      if (++jt > it) break;
    }

    // epilogue: normalize, write bf16 in place over Qb (own rows only)
#pragma unroll
    for (int reg = 0; reg < 4; ++reg) {
      const float rl = 1.0f / lrow[reg];
      unsigned short* orow = Qb + base + (size_t)(it * 64 + w * 16 + quad * 4 + reg) * 64;
#pragma unroll
      for (int dt = 0; dt < 4; ++dt)
        orow[dt * 16 + l16] = f2bf(oacc[dt][reg] * rl);
    }
  }
}

// ---------------------------------------------------------------------------
// Residual + LayerNorm; O is bf16.
// ---------------------------------------------------------------------------
__global__ __launch_bounds__(256) void ln_kernel(
    const float* __restrict__ x, const unsigned short* __restrict__ O,
    const float* __restrict__ gamma, const float* __restrict__ beta,
    float* __restrict__ out)
{
  __shared__ float red[8];
  const int row = blockIdx.x;
  const int tid = threadIdx.x;
  float4 xv = ((const float4*)x)[(size_t)row * 256 + tid];
  us4 ov4 = *(const us4*)(O + (size_t)row * 1024 + tid * 4);
  float4 y = make_float4(xv.x + bf2f(ov4[0]), xv.y + bf2f(ov4[1]),
                         xv.z + bf2f(ov4[2]), xv.w + bf2f(ov4[3]));
  float s1 = y.x + y.y + y.z + y.w;
  float s2 = y.x*y.x + y.y*y.y + y.z*y.z + y.w*y.w;
#pragma unroll
  for (int off = 32; off >= 1; off >>= 1) {
    s1 += __shfl_xor(s1, off, 64);
    s2 += __shfl_xor(s2, off, 64);
  }
  if ((tid & 63) == 0) { red[tid >> 6] = s1; red[4 + (tid >> 6)] = s2; }
  __syncthreads();
  s1 = red[0] + red[1] + red[2] + red[3];
  s2 = red[4] + red[5] + red[6] + red[7];
  const float mean = s1 * (1.0f / 1024.0f);
  const float var  = fmaxf(s2 * (1.0f / 1024.0f) - mean * mean, 0.f);
  const float rstd = 1.0f / (sqrtf(var) + 1e-8f);
  float4 gv = ((const float4*)gamma)[tid];
  float4 bv = ((const float4*)beta)[tid];
  float4 r;
  r.x = gv.x * (y.x - mean) * rstd + bv.x;
  r.y = gv.y * (y.y - mean) * rstd + bv.y;
  r.z = gv.z * (y.z - mean) * rstd + bv.z;
  r.w = gv.w * (y.w - mean) * rstd + bv.w;
  ((float4*)out)[(size_t)row * 256 + tid] = r;
}

// ---------------------------------------------------------------------------
extern "C" void kernel_launch(void* const* d_in, const int* in_sizes, int n_in,
                              void* d_out, int out_size, void* d_ws, size_t ws_size,
                              hipStream_t stream)
{
  const float* q  = (const float*)d_in[0];
  const float* k  = (const float*)d_in[1];
  const float* v  = (const float*)d_in[2];
  // d_in[3] = causal tril mask — applied analytically (j<=i)
  const int*   pad = (const int*)d_in[4];
  const float* Wq = (const float*)d_in[5];
  const float* bq = (const float*)d_in[6];
  const float* Wk = (const float*)d_in[7];
  const float* bk = (const float*)d_in[8];
  const float* Wv = (const float*)d_in[9];
  const float* bv = (const float*)d_in[10];
  const float* Wo = (const float*)d_in[11];
  const float* bo = (const float*)d_in[12];
  const float* gamma = (const float*)d_in[13];
  const float* beta  = (const float*)d_in[14];
  float* out = (float*)d_out;

  char* ws = (char*)d_ws;
  const size_t MB = 1024 * 1024;
  unsigned short* Ac   = (unsigned short*)(ws);             // 16 MB bf16 staging
  unsigned short* Qb   = (unsigned short*)(ws + 16 * MB);   // 16 MB
  unsigned short* Kb   = (unsigned short*)(ws + 32 * MB);   // 16 MB
  unsigned short* Vb   = (unsigned short*)(ws + 48 * MB);   // 16 MB (flat V)
  unsigned short* Vtb  = (unsigned short*)(ws + 64 * MB);   // 16 MB (V^T per bh)
  unsigned short* Wall = (unsigned short*)(ws + 80 * MB);   // 8 MB (4 weights bf16)
  unsigned short* Obuf = Ac;                                // alias: Ac dead after V-GEMM

  dim3 gg(8, 64), bb(256);
  cvt_w<<<dim3(1024, 4), 256, 0, stream>>>(Wq, Wk, Wv, Wo, Wall);

  cvt_a<<<8192, 256, 0, stream>>>(q, Ac);
  gemm_mfma<<<gg, bb, 0, stream>>>(Ac, Wall + 0 * MB, bq, Qb);
  cvt_a<<<8192, 256, 0, stream>>>(k, Ac);
  gemm_mfma<<<gg, bb, 0, stream>>>(Ac, Wall + 1 * MB, bk, Kb);
  cvt_a<<<8192, 256, 0, stream>>>(v, Ac);
  gemm_mfma<<<gg, bb, 0, stream>>>(Ac, Wall + 2 * MB, bv, Vb);
  vtrans<<<dim3(32, 64), 256, 0, stream>>>(Vb, Vtb);

  attn_mfma<<<dim3(16, 64), 256, 0, stream>>>(Qb, Kb, Vtb, pad);  // Qb <- attn out

  gemm_mfma<<<gg, bb, 0, stream>>>(Qb, Wall + 3 * MB, bo, Obuf);
  ln_kernel<<<dim3(B_ * S_), 256, 0, stream>>>(q, Obuf, gamma, beta, out);
}